// Round 8
// baseline (199.750 us; speedup 1.0000x reference)
//
#include <hip/hip_runtime.h>
#include <cstddef>
#include <cstdint>

typedef __attribute__((ext_vector_type(8))) short bf16x8;
typedef __attribute__((ext_vector_type(4))) float f32x4;

constexpr int BN    = 512;    // nodes per bucket
constexpr int CAPB  = 4096;   // per-bucket store capacity (mean 3265, +14 sigma)
constexpr int CHUNK = 4096;   // edges per bin block

__device__ __forceinline__ unsigned short tobf16(float f) {
    unsigned int u = __float_as_uint(f);
    u += 0x7fffu + ((u >> 16) & 1u);   // round to nearest even
    return (unsigned short)(u >> 16);
}
__device__ __forceinline__ float blo(unsigned int u) { return __uint_as_float(u << 16); }
__device__ __forceinline__ float bhi(unsigned int u) { return __uint_as_float(u & 0xffff0000u); }
__device__ __forceinline__ unsigned int pack2(float lo, float hi) {
    return (unsigned int)tobf16(lo) | ((unsigned int)tobf16(hi) << 16);
}
// a[k] += s * row[k]
__device__ __forceinline__ void acc8f(float* a, uint4 v, float s) {
    a[0] = fmaf(s, blo(v.x), a[0]); a[1] = fmaf(s, bhi(v.x), a[1]);
    a[2] = fmaf(s, blo(v.y), a[2]); a[3] = fmaf(s, bhi(v.y), a[3]);
    a[4] = fmaf(s, blo(v.z), a[4]); a[5] = fmaf(s, bhi(v.z), a[5]);
    a[6] = fmaf(s, blo(v.w), a[6]); a[7] = fmaf(s, bhi(v.w), a[7]);
}

// ---------------- init: zero cursor + convert/transpose weights ----------------

__global__ __launch_bounds__(256)
void init_k(int* __restrict__ cursor,
            const float* __restrict__ W1, unsigned short* __restrict__ W1T,
            const float* __restrict__ W2, unsigned short* __restrict__ W2T) {
    int b = blockIdx.x, t = threadIdx.x;
    if (b == 96) { cursor[t] = 0; return; }
    int idx = b * 256 + t;                 // 24576 total
    if (idx < 16384) {                     // W1 [128x128] -> W1T[n][k]
        int k = idx >> 7, n = idx & 127;
        W1T[n * 128 + k] = tobf16(W1[idx]);
    } else {                               // W2 [128x64] -> W2T[n][k]
        int j = idx - 16384;
        int k = j >> 6, n = j & 63;
        W2T[n * 128 + k] = tobf16(W2[j]);
    }
}

// ---------------- fused: LDS-free gemm1 + edge binning ----------------
// blocks [0,gb1): hs1 = bf16(x @ W1). One 16-row tile per wave, A-frags
// straight from global x (fp32->bf16 in reg), B-frags from L1-resident W1T.
// blocks [gb1,gb1+nbin): multi-split bin of a 4096-edge chunk.

__global__ __launch_bounds__(256)
void bin_gemm1_k(const float* __restrict__ x, const unsigned short* __restrict__ W1T,
                 unsigned short* __restrict__ hs1, int M,
                 const int* __restrict__ esrc, const int* __restrict__ edst,
                 int* __restrict__ cursor, int* __restrict__ store, int E,
                 int gb1, int nbuck) {
    __shared__ int hist[256];
    __shared__ int bbase[256];
    int b = blockIdx.x, t = threadIdx.x;

    if (b >= gb1) {
        // ---- bin branch ----
        hist[t] = 0;
        __syncthreads();
        int base = (b - gb1) * CHUNK;
        int nloc = min(CHUNK, E - base);
        int lh[16];
#pragma unroll
        for (int j = 0; j < 16; ++j) {
            int i = j * 256 + t;
            if (i < nloc) lh[j] = atomicAdd(&hist[edst[base + i] >> 9], 1);
        }
        __syncthreads();
        if (t < nbuck) bbase[t] = hist[t] ? atomicAdd(&cursor[t], hist[t]) : 0;
        __syncthreads();
#pragma unroll
        for (int j = 0; j < 16; ++j) {
            int i = j * 256 + t;
            if (i < nloc) {
                int e = base + i;
                int s = esrc[e], d = edst[e];
                int bk = d >> 9;
                int pos = bbase[bk] + lh[j];
                if (pos < CAPB) store[bk * CAPB + pos] = (s << 9) | (d & (BN - 1));
            }
        }
        return;
    }

    // ---- gemm1 branch: no LDS, no syncthreads ----
    const int lane = t & 63;
    const int w = t >> 6;
    const int l15 = lane & 15;
    const int quad = lane >> 4;

    int row0 = (b * 4 + w) * 16;           // 16-row tile per wave
    if (row0 >= M) return;
    int rowA = min(row0 + l15, M - 1);     // clamped load row (no OOB)

    bf16x8 af[4];
    const float* xr = x + (size_t)rowA * 128 + quad * 8;
#pragma unroll
    for (int kt = 0; kt < 4; ++kt) {
        float4 f0 = *(const float4*)(xr + kt * 32);
        float4 f1 = *(const float4*)(xr + kt * 32 + 4);
        unsigned short tmp[8];
        tmp[0] = tobf16(f0.x); tmp[1] = tobf16(f0.y);
        tmp[2] = tobf16(f0.z); tmp[3] = tobf16(f0.w);
        tmp[4] = tobf16(f1.x); tmp[5] = tobf16(f1.y);
        tmp[6] = tobf16(f1.z); tmp[7] = tobf16(f1.w);
        af[kt] = *(bf16x8*)tmp;
    }

    f32x4 acc[8] = {};
    const unsigned short* bp = W1T + l15 * 128 + quad * 8;
#pragma unroll
    for (int ct = 0; ct < 8; ++ct) {
#pragma unroll
        for (int kt = 0; kt < 4; ++kt) {
            bf16x8 bb = *(const bf16x8*)(bp + ct * 16 * 128 + kt * 32);
            acc[ct] = __builtin_amdgcn_mfma_f32_16x16x32_bf16(af[kt], bb, acc[ct], 0, 0, 0);
        }
    }

#pragma unroll
    for (int reg = 0; reg < 4; ++reg) {
        int row = row0 + quad * 4 + reg;
        if (row < M) {
#pragma unroll
            for (int ct = 0; ct < 8; ++ct) {
                hs1[(size_t)row * 128 + ct * 16 + l15] = tobf16(acc[ct][reg]);
            }
        }
    }
}

// ---------------- per-bucket count/scan/fill ----------------

__global__ __launch_bounds__(256)
void build_k(const int* __restrict__ cursor, const int* __restrict__ store,
             float* __restrict__ dinv, int* __restrict__ offsets,
             int* __restrict__ csr, int M, int nbuck) {
    __shared__ int eds[CAPB];
    __shared__ int cnts[BN];
    __shared__ int offs[BN];
    __shared__ int ps[256];
    __shared__ int sgbase;

    int b = blockIdx.x, t = threadIdx.x;

    int cv = (t < nbuck) ? min(cursor[t], CAPB) : 0;
    ps[t] = cv;
    __syncthreads();
    for (int off = 1; off < 256; off <<= 1) {
        int v = (t >= off) ? ps[t - off] : 0;
        __syncthreads();
        ps[t] += v;
        __syncthreads();
    }
    if (t == b) sgbase = ps[t] - cv;
    if (b == nbuck - 1 && t == nbuck - 1) offsets[M] = ps[t];
    __syncthreads();
    int gbase = sgbase;
    int nE = min(cursor[b], CAPB);

    for (int i = t; i < nE; i += 256) eds[i] = store[b * CAPB + i];
    for (int l = t; l < BN; l += 256) cnts[l] = 0;
    __syncthreads();

    for (int i = t; i < nE; i += 256) atomicAdd(&cnts[eds[i] & (BN - 1)], 1);
    __syncthreads();

    int a0 = cnts[2 * t], a1 = cnts[2 * t + 1];
    int pair = a0 + a1;
    ps[t] = pair;
    __syncthreads();
    for (int off = 1; off < 256; off <<= 1) {
        int v = (t >= off) ? ps[t - off] : 0;
        __syncthreads();
        ps[t] += v;
        __syncthreads();
    }
    int excl = ps[t] - pair;
    offs[2 * t] = excl;
    offs[2 * t + 1] = excl + a0;
    __syncthreads();

    int node0 = b * BN;
    for (int l = t; l < BN; l += 256) {
        int node = node0 + l;
        if (node < M) {
            dinv[node] = rsqrtf(1.0f + (float)cnts[l]);
            offsets[node] = gbase + offs[l];
        }
    }
    __syncthreads();

    for (int i = t; i < nE; i += 256) {
        int pk = eds[i];
        int pos = atomicAdd(&offs[pk & (BN - 1)], 1);
        csr[gbase + pos] = pk >> 9;
    }
}

// ---------------- fused: aggregate(hs1)+bias+ReLU -> LDS -> GEMM2 ----------------
// 1024 threads (16 waves): 2 blocks/CU = 32 waves/CU during the latency-bound
// gather. Aggregation: 2 passes x 64 node-groups (16 lanes/node), unroll x4.

__global__ __launch_bounds__(1024)
void agg_gemm2_k(const unsigned short* __restrict__ hs1, const int* __restrict__ offsets,
                 const int* __restrict__ csr, const float* __restrict__ dinv,
                 const float* __restrict__ b1, const unsigned short* __restrict__ W2T,
                 unsigned short* __restrict__ hs2, int M) {
    __shared__ __align__(16) unsigned short As[128 * 136];   // 34.8 KB
    __shared__ __align__(16) unsigned short Bs[64 * 136];    // 17.4 KB

    int t = threadIdx.x;
    const int rowBase = blockIdx.x * 128;

    {
        int nn = t >> 4;
        int c8 = (t & 15) * 8;
        *(uint4*)(&Bs[nn * 136 + c8]) = *(const uint4*)(W2T + nn * 128 + c8);
    }

    const uint4* rows = (const uint4*)hs1;
    int f8 = t & 15;
#pragma unroll
    for (int pass = 0; pass < 2; ++pass) {
        int r = pass * 64 + (t >> 4);
        int node = rowBase + r;
        uint4 ov = make_uint4(0, 0, 0, 0);
        if (node < M) {
            float a[8] = {0, 0, 0, 0, 0, 0, 0, 0};
            float dvi = dinv[node];
            acc8f(a, rows[(size_t)node * 16 + f8], dvi);   // self loop
            int k = offsets[node], end = offsets[node + 1];
            for (; k + 4 <= end; k += 4) {
                int s0 = csr[k], s1 = csr[k + 1], s2 = csr[k + 2], s3 = csr[k + 3];
                uint4 v0 = rows[(size_t)s0 * 16 + f8];
                uint4 v1 = rows[(size_t)s1 * 16 + f8];
                uint4 v2 = rows[(size_t)s2 * 16 + f8];
                uint4 v3 = rows[(size_t)s3 * 16 + f8];
                float d0 = dinv[s0], d1 = dinv[s1], d2 = dinv[s2], d3 = dinv[s3];
                acc8f(a, v0, d0); acc8f(a, v1, d1);
                acc8f(a, v2, d2); acc8f(a, v3, d3);
            }
            for (; k < end; ++k) {
                int s0 = csr[k];
                acc8f(a, rows[(size_t)s0 * 16 + f8], dinv[s0]);
            }
            const float* bp = b1 + f8 * 8;
            float4 bA = *(const float4*)bp;
            float4 bB = *(const float4*)(bp + 4);
            float r0 = fmaxf(fmaf(a[0], dvi, bA.x), 0.f);
            float r1 = fmaxf(fmaf(a[1], dvi, bA.y), 0.f);
            float r2 = fmaxf(fmaf(a[2], dvi, bA.z), 0.f);
            float r3 = fmaxf(fmaf(a[3], dvi, bA.w), 0.f);
            float r4 = fmaxf(fmaf(a[4], dvi, bB.x), 0.f);
            float r5 = fmaxf(fmaf(a[5], dvi, bB.y), 0.f);
            float r6 = fmaxf(fmaf(a[6], dvi, bB.z), 0.f);
            float r7 = fmaxf(fmaf(a[7], dvi, bB.w), 0.f);
            ov.x = pack2(r0, r1); ov.y = pack2(r2, r3);
            ov.z = pack2(r4, r5); ov.w = pack2(r6, r7);
        }
        *(uint4*)(&As[r * 136 + f8 * 8]) = ov;
    }
    __syncthreads();

    const int lane = t & 63;
    const int w = t >> 6;          // 0..15
    const int l15 = lane & 15;
    const int quad = lane >> 4;
    const int rt = w >> 1;
    const int ch = (w & 1) * 2;

    f32x4 acc[2] = {};
    const unsigned short* ap = &As[(rt * 16 + l15) * 136 + quad * 8];
    const unsigned short* bp = &Bs[l15 * 136 + quad * 8];
#pragma unroll
    for (int kt = 0; kt < 4; ++kt) {
        bf16x8 av = *(const bf16x8*)(ap + kt * 32);
#pragma unroll
        for (int c = 0; c < 2; ++c) {
            bf16x8 bb = *(const bf16x8*)(bp + (ch + c) * 16 * 136 + kt * 32);
            acc[c] = __builtin_amdgcn_mfma_f32_16x16x32_bf16(av, bb, acc[c], 0, 0, 0);
        }
    }
#pragma unroll
    for (int reg = 0; reg < 4; ++reg) {
        int row = rowBase + rt * 16 + quad * 4 + reg;
        if (row < M) {
#pragma unroll
            for (int c = 0; c < 2; ++c) {
                hs2[(size_t)row * 64 + (ch + c) * 16 + l15] = tobf16(acc[c][reg]);
            }
        }
    }
}

// ---------------- gather-aggregate layer2 + bias + log_softmax (F=64) ----------------

__global__ __launch_bounds__(256)
void gather_lsm_k(const unsigned short* __restrict__ hs, const int* __restrict__ offsets,
                  const int* __restrict__ csr, const float* __restrict__ dinv,
                  const float* __restrict__ bias, float* __restrict__ out, int n) {
    int t = threadIdx.x;
    int node = blockIdx.x * 32 + (t >> 3);
    int f8 = t & 7;
    if (node >= n) return;
    const uint4* rows = (const uint4*)hs;
    float a[8] = {0, 0, 0, 0, 0, 0, 0, 0};
    float dvi = dinv[node];
    acc8f(a, rows[(size_t)node * 8 + f8], dvi);
    int k = offsets[node], end = offsets[node + 1];
    for (; k + 4 <= end; k += 4) {
        int s0 = csr[k], s1 = csr[k + 1], s2 = csr[k + 2], s3 = csr[k + 3];
        uint4 v0 = rows[(size_t)s0 * 8 + f8];
        uint4 v1 = rows[(size_t)s1 * 8 + f8];
        uint4 v2 = rows[(size_t)s2 * 8 + f8];
        uint4 v3 = rows[(size_t)s3 * 8 + f8];
        float d0 = dinv[s0], d1 = dinv[s1], d2 = dinv[s2], d3 = dinv[s3];
        acc8f(a, v0, d0); acc8f(a, v1, d1);
        acc8f(a, v2, d2); acc8f(a, v3, d3);
    }
    for (; k < end; ++k) {
        int s0 = csr[k];
        acc8f(a, rows[(size_t)s0 * 8 + f8], dinv[s0]);
    }

    const float* bp = bias + f8 * 8;
    float4 bA = *(const float4*)bp;
    float4 bB = *(const float4*)(bp + 4);
    float v0 = fmaf(a[0], dvi, bA.x), v1 = fmaf(a[1], dvi, bA.y);
    float v2 = fmaf(a[2], dvi, bA.z), v3 = fmaf(a[3], dvi, bA.w);
    float v4 = fmaf(a[4], dvi, bB.x), v5 = fmaf(a[5], dvi, bB.y);
    float v6 = fmaf(a[6], dvi, bB.z), v7 = fmaf(a[7], dvi, bB.w);

    float m = fmaxf(fmaxf(fmaxf(v0, v1), fmaxf(v2, v3)), fmaxf(fmaxf(v4, v5), fmaxf(v6, v7)));
#pragma unroll
    for (int off = 1; off < 8; off <<= 1) m = fmaxf(m, __shfl_xor(m, off, 8));
    float e = expf(v0 - m) + expf(v1 - m) + expf(v2 - m) + expf(v3 - m)
            + expf(v4 - m) + expf(v5 - m) + expf(v6 - m) + expf(v7 - m);
#pragma unroll
    for (int off = 1; off < 8; off <<= 1) e += __shfl_xor(e, off, 8);
    float l = m + logf(e);

    float* op = out + (size_t)node * 64 + f8 * 8;
    *(float4*)op       = make_float4(v0 - l, v1 - l, v2 - l, v3 - l);
    *(float4*)(op + 4) = make_float4(v4 - l, v5 - l, v6 - l, v7 - l);
}

// ---------------- launch ----------------

extern "C" void kernel_launch(void* const* d_in, const int* in_sizes, int n_in,
                              void* d_out, int out_size, void* d_ws, size_t ws_size,
                              hipStream_t stream) {
    const float* x  = (const float*)d_in[0];
    const int*   eg = (const int*)d_in[1];
    const float* W1 = (const float*)d_in[2];
    const float* b1 = (const float*)d_in[3];
    const float* W2 = (const float*)d_in[4];
    const float* b2 = (const float*)d_in[5];
    float* out = (float*)d_out;

    const int M = in_sizes[0] / 128;       // 100000
    const int E = in_sizes[1] / 2;         // 640000
    const int* esrc = eg;
    const int* edst = eg + E;
    const int NBUCK = (M + BN - 1) / BN;        // 196
    const int nbin  = (E + CHUNK - 1) / CHUNK;  // 157

    // workspace carve-up
    int* cursor  = (int*)d_ws;                             // [256]
    int* store   = cursor + 256;                           // [NBUCK*CAPB]
    int* offsets = store + (size_t)NBUCK * CAPB;           // [M+1]
    int* csr     = offsets + M + 1;                        // [E]
    uintptr_t p = (uintptr_t)(csr + E);
    p = (p + 255) & ~(uintptr_t)255;
    float* dinv = (float*)p;                               // [M]
    p = (uintptr_t)(dinv + M);
    p = (p + 255) & ~(uintptr_t)255;
    unsigned short* hs1 = (unsigned short*)p;              // [M*128] bf16
    unsigned short* hs2 = hs1 + (size_t)M * 128;           // [M*64]  bf16
    unsigned short* W1T = hs2 + (size_t)M * 64;            // [128*128]
    unsigned short* W2T = W1T + 128 * 128;                 // [64*128]

    const int gb1 = (M + 63) / 64;         // 1563 (64 rows/block, 16/wave)
    const int gb2 = (M + 127) / 128;       // 782

    init_k<<<97, 256, 0, stream>>>(cursor, W1, W1T, W2, W2T);
    bin_gemm1_k<<<gb1 + nbin, 256, 0, stream>>>(x, W1T, hs1, M, esrc, edst,
                                                cursor, store, E, gb1, NBUCK);
    build_k<<<NBUCK, 256, 0, stream>>>(cursor, store, dinv, offsets, csr, M, NBUCK);
    agg_gemm2_k<<<gb2, 1024, 0, stream>>>(hs1, offsets, csr, dinv, b1, W2T, hs2, M);
    gather_lsm_k<<<(M + 31) / 32, 256, 0, stream>>>(hs2, offsets, csr, dinv, b2, out, M);
}